// Round 1
// baseline (122.981 us; speedup 1.0000x reference)
//
#include <hip/hip_runtime.h>

// CTPN loss: gather 64 pos + 64 neg anchors from [1,2K,H,W] tensors,
// CE over 2 logits + SmoothL1 regression + masked side SmoothL1, reduce to
// 4 scalars. One block, 128 threads (2 waves), shuffle + LDS reduction.

#define HH 512
#define WW 1024
#define KK 10
#define NPOS 64
#define NNEG 64

__device__ __forceinline__ float smooth_l1(float d) {
    float a = fabsf(d);
    return (a < 1.0f) ? (0.5f * a * a) : (a - 0.5f);
}

__global__ void ctpn_loss_kernel(const float* __restrict__ scores,
                                 const float* __restrict__ vcoords,
                                 const float* __restrict__ sides,
                                 const int* __restrict__ pos_y,
                                 const int* __restrict__ pos_x,
                                 const int* __restrict__ pos_z,
                                 const int* __restrict__ neg_y,
                                 const int* __restrict__ neg_x,
                                 const int* __restrict__ neg_z,
                                 const float* __restrict__ v_targets,
                                 const int* __restrict__ side_mask,
                                 const float* __restrict__ side_targets,
                                 float* __restrict__ out) {
    const int t = threadIdx.x;          // 0..127
    const int HW = HH * WW;

    float cls = 0.0f, vsum = 0.0f, ssum = 0.0f, cnt = 0.0f;

    if (t < NPOS) {
        const int y = pos_y[t], x = pos_x[t], z = pos_z[t];
        const int base = (2 * z) * HW + y * WW + x;   // channel 2z; 2z+1 is +HW
        const float s0 = scores[base];
        const float s1 = scores[base + HW];
        const float m  = fmaxf(s0, s1);
        const float lse = m + logf(expf(s0 - m) + expf(s1 - m));
        cls = lse - s1;                               // -log_softmax[1]

        const float v0 = vcoords[base];
        const float v1 = vcoords[base + HW];
        vsum = smooth_l1(v0 - v_targets[2 * t])
             + smooth_l1(v1 - v_targets[2 * t + 1]);

        const float sp = sides[z * HW + y * WW + x];
        const float mm = (float)side_mask[t];
        ssum = smooth_l1(sp - side_targets[t]) * mm;
        cnt  = mm;
    } else {
        const int i = t - NPOS;
        const int y = neg_y[i], x = neg_x[i], z = neg_z[i];
        const int base = (2 * z) * HW + y * WW + x;
        const float s0 = scores[base];
        const float s1 = scores[base + HW];
        const float m  = fmaxf(s0, s1);
        const float lse = m + logf(expf(s0 - m) + expf(s1 - m));
        cls = lse - s0;                               // -log_softmax[0]
    }

    // Wave (64-lane) butterfly-free down-shuffle reduction
    #pragma unroll
    for (int off = 32; off > 0; off >>= 1) {
        cls  += __shfl_down(cls,  off, 64);
        vsum += __shfl_down(vsum, off, 64);
        ssum += __shfl_down(ssum, off, 64);
        cnt  += __shfl_down(cnt,  off, 64);
    }

    __shared__ float red[2][4];
    if ((t & 63) == 0) {
        const int w = t >> 6;
        red[w][0] = cls; red[w][1] = vsum; red[w][2] = ssum; red[w][3] = cnt;
    }
    __syncthreads();

    if (t == 0) {
        const float cls_total = red[0][0] + red[1][0];
        const float v_total   = red[0][1] + red[1][1];
        const float s_total   = red[0][2] + red[1][2];
        const float c_total   = red[0][3] + red[1][3];

        const float avg_cls = cls_total / (float)(NPOS + NNEG);
        const float avg_v   = v_total   / (float)(NPOS * 2);
        const float avg_o   = (c_total > 0.0f) ? (s_total / fmaxf(c_total, 1.0f)) : 0.0f;

        out[0] = avg_cls + 1.0f * avg_v + 2.0f * avg_o;  // lambda1=1, lambda2=2
        out[1] = avg_cls;
        out[2] = avg_v;
        out[3] = avg_o;
    }
}

extern "C" void kernel_launch(void* const* d_in, const int* in_sizes, int n_in,
                              void* d_out, int out_size, void* d_ws, size_t ws_size,
                              hipStream_t stream) {
    const float* scores       = (const float*)d_in[0];
    const float* vcoords      = (const float*)d_in[1];
    const float* sides        = (const float*)d_in[2];
    const int*   pos_y        = (const int*)d_in[3];
    const int*   pos_x        = (const int*)d_in[4];
    const int*   pos_z        = (const int*)d_in[5];
    const int*   neg_y        = (const int*)d_in[6];
    const int*   neg_x        = (const int*)d_in[7];
    const int*   neg_z        = (const int*)d_in[8];
    const float* v_targets    = (const float*)d_in[9];
    const int*   side_mask    = (const int*)d_in[10];
    const float* side_targets = (const float*)d_in[11];
    float* out = (float*)d_out;

    ctpn_loss_kernel<<<1, 128, 0, stream>>>(scores, vcoords, sides,
                                            pos_y, pos_x, pos_z,
                                            neg_y, neg_x, neg_z,
                                            v_targets, side_mask, side_targets,
                                            out);
}